// Round 2
// baseline (99.845 us; speedup 1.0000x reference)
//
#include <hip/hip_runtime.h>
#include <math.h>

#define BS   8
#define HW   1024
#define NP   512     // model points
#define NS   51      // hw / STEP samples
#define STEP 20
#define SW   0.01f
#define HDR  16      // floats reserved at front of ws (64 B): [0]=float acc, [1]=uint counter
#define BSTRIDE (3*NP) // floats per batch of transformed GT cloud in ws

// ---------------------------------------------------------------------------
// K1: transform GT cloud per batch into d_ws (SoA gx[512],gy[512],gz[512]),
//     and zero the accumulator/counter header. 8 blocks x 128 threads.
// ---------------------------------------------------------------------------
__global__ __launch_bounds__(128) void prep_kernel(
    const float* __restrict__ gt_r,      // (BS,3,3)
    const float* __restrict__ gt_t,      // (BS,3)
    const float* __restrict__ model_xyz, // (BS,3,NP)
    float* __restrict__ ws)
{
    const int b = blockIdx.x;
    const int tid = threadIdx.x;
    if (b == 0 && tid == 0) {
        ws[0] = 0.0f;
        ((unsigned int*)ws)[1] = 0u;
    }
    const float* Rg = gt_r + b * 9;
    const float g00 = Rg[0], g01 = Rg[1], g02 = Rg[2];
    const float g10 = Rg[3], g11 = Rg[4], g12 = Rg[5];
    const float g20 = Rg[6], g21 = Rg[7], g22 = Rg[8];
    const float tx = gt_t[b*3+0], ty = gt_t[b*3+1], tz = gt_t[b*3+2];
    const float* M = model_xyz + b * 3 * NP;
    float* gx = ws + HDR + b * BSTRIDE;
    float* gy = gx + NP;
    float* gz = gx + 2 * NP;
    #pragma unroll
    for (int p = tid; p < NP; p += 128) {
        const float mx = M[p], my = M[NP + p], mz = M[2*NP + p];
        gx[p] = fmaf(g00, mx, fmaf(g01, my, fmaf(g02, mz, tx)));
        gy[p] = fmaf(g10, mx, fmaf(g11, my, fmaf(g12, mz, ty)));
        gz[p] = fmaf(g20, mx, fmaf(g21, my, fmaf(g22, mz, tz)));
    }
}

// ---------------------------------------------------------------------------
// K2: one block per (b,n). Each thread owns 2 predicted points, scans the
//     512-point GT cloud via uniform float4 global loads (scalar-cache path),
//     4 independent min chains per point. Block reduce, atomic accumulate,
//     last block finalizes into d_out.
// ---------------------------------------------------------------------------
__global__ __launch_bounds__(256) void scan_kernel(
    const float* __restrict__ pred_r,    // (BS,4,HW)
    const float* __restrict__ pred_t,    // (BS,3,HW)
    const float* __restrict__ pred_s,    // (BS,HW)
    const float* __restrict__ model_xyz, // (BS,3,NP)
    const float* __restrict__ ws_ro,     // transformed GT cloud (read)
    float* __restrict__ ws,              // header (atomics)
    float* __restrict__ out)
{
    const int bn  = blockIdx.x;       // 0..407
    const int b   = bn / NS;
    const int n   = bn % NS;
    const int pix = n * STEP;
    const int tid = threadIdx.x;

    // Quaternion -> rotation for this (b,n)
    float q0 = pred_r[(b*4 + 0)*HW + pix];
    float q1 = pred_r[(b*4 + 1)*HW + pix];
    float q2 = pred_r[(b*4 + 2)*HW + pix];
    float q3 = pred_r[(b*4 + 3)*HW + pix];
    const float inv = rsqrtf(q0*q0 + q1*q1 + q2*q2 + q3*q3);
    q0 *= inv; q1 *= inv; q2 *= inv; q3 *= inv;
    const float r00 = 1.f - 2.f*(q2*q2 + q3*q3);
    const float r01 = 2.f*q1*q2 - 2.f*q0*q3;
    const float r02 = 2.f*q0*q2 + 2.f*q1*q3;
    const float r10 = 2.f*q1*q2 + 2.f*q3*q0;
    const float r11 = 1.f - 2.f*(q1*q1 + q3*q3);
    const float r12 = -2.f*q0*q1 + 2.f*q2*q3;
    const float r20 = -2.f*q0*q2 + 2.f*q1*q3;
    const float r21 = 2.f*q0*q1 + 2.f*q2*q3;
    const float r22 = 1.f - 2.f*(q1*q1 + q2*q2);
    const float ptx = pred_t[(b*3 + 0)*HW + pix];
    const float pty = pred_t[(b*3 + 1)*HW + pix];
    const float ptz = pred_t[(b*3 + 2)*HW + pix];

    const float* M = model_xyz + b * 3 * NP;
    const int p0 = tid, p1 = tid + 256;
    const float mx0 = M[p0], my0 = M[NP + p0], mz0 = M[2*NP + p0];
    const float mx1 = M[p1], my1 = M[NP + p1], mz1 = M[2*NP + p1];
    const float px0 = fmaf(r00, mx0, fmaf(r01, my0, fmaf(r02, mz0, ptx)));
    const float py0 = fmaf(r10, mx0, fmaf(r11, my0, fmaf(r12, mz0, pty)));
    const float pz0 = fmaf(r20, mx0, fmaf(r21, my0, fmaf(r22, mz0, ptz)));
    const float px1 = fmaf(r00, mx1, fmaf(r01, my1, fmaf(r02, mz1, ptx)));
    const float py1 = fmaf(r10, mx1, fmaf(r11, my1, fmaf(r12, mz1, pty)));
    const float pz1 = fmaf(r20, mx1, fmaf(r21, my1, fmaf(r22, mz1, ptz)));

    // Uniform-index scan of GT cloud (block-uniform pointer + loop index)
    const float4* __restrict__ gx4 = (const float4*)(ws_ro + HDR + b * BSTRIDE);
    const float4* __restrict__ gy4 = gx4 + NP/4;
    const float4* __restrict__ gz4 = gy4 + NP/4;

    const float BIG = 3.4e38f;
    float4 m0 = make_float4(BIG, BIG, BIG, BIG);
    float4 m1 = make_float4(BIG, BIG, BIG, BIG);

    #pragma unroll 4
    for (int j = 0; j < NP/4; ++j) {
        const float4 X = gx4[j];
        const float4 Y = gy4[j];
        const float4 Z = gz4[j];
        float dx, dy, dz, d2;
        // point 0, four independent min chains
        dx = px0 - X.x; dy = py0 - Y.x; dz = pz0 - Z.x;
        d2 = fmaf(dx, dx, fmaf(dy, dy, dz*dz)); m0.x = fminf(m0.x, d2);
        dx = px0 - X.y; dy = py0 - Y.y; dz = pz0 - Z.y;
        d2 = fmaf(dx, dx, fmaf(dy, dy, dz*dz)); m0.y = fminf(m0.y, d2);
        dx = px0 - X.z; dy = py0 - Y.z; dz = pz0 - Z.z;
        d2 = fmaf(dx, dx, fmaf(dy, dy, dz*dz)); m0.z = fminf(m0.z, d2);
        dx = px0 - X.w; dy = py0 - Y.w; dz = pz0 - Z.w;
        d2 = fmaf(dx, dx, fmaf(dy, dy, dz*dz)); m0.w = fminf(m0.w, d2);
        // point 1
        dx = px1 - X.x; dy = py1 - Y.x; dz = pz1 - Z.x;
        d2 = fmaf(dx, dx, fmaf(dy, dy, dz*dz)); m1.x = fminf(m1.x, d2);
        dx = px1 - X.y; dy = py1 - Y.y; dz = pz1 - Z.y;
        d2 = fmaf(dx, dx, fmaf(dy, dy, dz*dz)); m1.y = fminf(m1.y, d2);
        dx = px1 - X.z; dy = py1 - Y.z; dz = pz1 - Z.z;
        d2 = fmaf(dx, dx, fmaf(dy, dy, dz*dz)); m1.z = fminf(m1.z, d2);
        dx = px1 - X.w; dy = py1 - Y.w; dz = pz1 - Z.w;
        d2 = fmaf(dx, dx, fmaf(dy, dy, dz*dz)); m1.w = fminf(m1.w, d2);
    }
    const float dmin0 = fminf(fminf(m0.x, m0.y), fminf(m0.z, m0.w));
    const float dmin1 = fminf(fminf(m1.x, m1.y), fminf(m1.z, m1.w));

    float sum = sqrtf(fmaxf(dmin0, 0.f)) + sqrtf(fmaxf(dmin1, 0.f));

    // Block reduction: wave shuffle (width 64), then LDS across 4 waves
    for (int off = 32; off; off >>= 1) sum += __shfl_down(sum, off, 64);
    __shared__ float wsum[4];
    if ((tid & 63) == 0) wsum[tid >> 6] = sum;
    __syncthreads();
    if (tid == 0) {
        const float s = wsum[0] + wsum[1] + wsum[2] + wsum[3];
        const float add_ij = s * (1.f / NP);
        const float ps = pred_s[b * HW + pix];
        const float term = add_ij * ps - SW * logf(ps);
        atomicAdd(ws, term);
        __threadfence();
        const unsigned int old = atomicAdd(((unsigned int*)ws) + 1, 1u);
        if (old == (unsigned int)(BS * NS - 1)) {
            float total = atomicAdd(ws, 0.0f);   // RMW read: sees all 408 adds
            total *= 1.f / (float)(BS * NS);
            if (isinf(total) || isnan(total)) total = 0.f;
            out[0] = total;
        }
    }
}

extern "C" void kernel_launch(void* const* d_in, const int* in_sizes, int n_in,
                              void* d_out, int out_size, void* d_ws, size_t ws_size,
                              hipStream_t stream) {
    const float* pred_r    = (const float*)d_in[0];
    const float* pred_t    = (const float*)d_in[1];
    const float* pred_s    = (const float*)d_in[2];
    // d_in[3] = mask (all ones; reference ignores it)
    const float* gt_r      = (const float*)d_in[4];
    const float* gt_t      = (const float*)d_in[5];
    const float* model_xyz = (const float*)d_in[6];
    // d_in[7] = cls_ids (unused)

    float* ws  = (float*)d_ws;
    float* out = (float*)d_out;

    prep_kernel<<<BS, 128, 0, stream>>>(gt_r, gt_t, model_xyz, ws);
    scan_kernel<<<BS * NS, 256, 0, stream>>>(
        pred_r, pred_t, pred_s, model_xyz, ws, ws, out);
}

// Round 3
// 82.156 us; speedup vs baseline: 1.2153x; 1.2153x over previous
//
#include <hip/hip_runtime.h>
#include <math.h>

#define BS   8
#define HW   1024
#define NP   512     // model points
#define NS   51      // hw / STEP samples
#define STEP 20
#define SW   0.01f

// One block per (b, n) sample pair. 256 threads. Fused: GT transform staged
// in LDS as float4 (-2gx, -2gy, -2gz, |g|^2); inner loop is 3 fma + 1 min
// per (pred, gt) pair via d2 = |p|^2 + (|g|^2 - 2 p.g).
__global__ __launch_bounds__(256) void add_loss_kernel(
    const float* __restrict__ pred_r,    // (BS,4,HW)
    const float* __restrict__ pred_t,    // (BS,3,HW)
    const float* __restrict__ pred_s,    // (BS,HW)
    const float* __restrict__ gt_r,      // (BS,3,3)
    const float* __restrict__ gt_t,      // (BS,3)
    const float* __restrict__ model_xyz, // (BS,3,NP)
    float* __restrict__ partials)        // (BS*NS)
{
    const int bn  = blockIdx.x;      // 0..407
    const int b   = bn / NS;
    const int n   = bn % NS;
    const int pix = n * STEP;
    const int tid = threadIdx.x;

    __shared__ float4 g4[NP];        // 8 KB

    const float* Rg = gt_r + b * 9;
    const float g00 = Rg[0], g01 = Rg[1], g02 = Rg[2];
    const float g10 = Rg[3], g11 = Rg[4], g12 = Rg[5];
    const float g20 = Rg[6], g21 = Rg[7], g22 = Rg[8];
    const float tx = gt_t[b*3+0], ty = gt_t[b*3+1], tz = gt_t[b*3+2];
    const float* M = model_xyz + b * 3 * NP;

    // Stage transformed GT cloud into LDS (2 points per thread)
    #pragma unroll
    for (int p = tid; p < NP; p += 256) {
        const float mx = M[p], my = M[NP + p], mz = M[2*NP + p];
        const float gx = fmaf(g00, mx, fmaf(g01, my, fmaf(g02, mz, tx)));
        const float gy = fmaf(g10, mx, fmaf(g11, my, fmaf(g12, mz, ty)));
        const float gz = fmaf(g20, mx, fmaf(g21, my, fmaf(g22, mz, tz)));
        const float gn = fmaf(gx, gx, fmaf(gy, gy, gz*gz));
        g4[p] = make_float4(-2.f*gx, -2.f*gy, -2.f*gz, gn);
    }

    // Quaternion -> rotation for this (b,n)
    float q0 = pred_r[(b*4 + 0)*HW + pix];
    float q1 = pred_r[(b*4 + 1)*HW + pix];
    float q2 = pred_r[(b*4 + 2)*HW + pix];
    float q3 = pred_r[(b*4 + 3)*HW + pix];
    const float inv = rsqrtf(q0*q0 + q1*q1 + q2*q2 + q3*q3);
    q0 *= inv; q1 *= inv; q2 *= inv; q3 *= inv;
    const float r00 = 1.f - 2.f*(q2*q2 + q3*q3);
    const float r01 = 2.f*q1*q2 - 2.f*q0*q3;
    const float r02 = 2.f*q0*q2 + 2.f*q1*q3;
    const float r10 = 2.f*q1*q2 + 2.f*q3*q0;
    const float r11 = 1.f - 2.f*(q1*q1 + q3*q3);
    const float r12 = -2.f*q0*q1 + 2.f*q2*q3;
    const float r20 = -2.f*q0*q2 + 2.f*q1*q3;
    const float r21 = 2.f*q0*q1 + 2.f*q2*q3;
    const float r22 = 1.f - 2.f*(q1*q1 + q2*q2);
    const float ptx = pred_t[(b*3 + 0)*HW + pix];
    const float pty = pred_t[(b*3 + 1)*HW + pix];
    const float ptz = pred_t[(b*3 + 2)*HW + pix];

    // Each thread owns 2 predicted points: tid and tid+256
    const int p0 = tid, p1 = tid + 256;
    const float mx0 = M[p0], my0 = M[NP + p0], mz0 = M[2*NP + p0];
    const float mx1 = M[p1], my1 = M[NP + p1], mz1 = M[2*NP + p1];
    const float px0 = fmaf(r00, mx0, fmaf(r01, my0, fmaf(r02, mz0, ptx)));
    const float py0 = fmaf(r10, mx0, fmaf(r11, my0, fmaf(r12, mz0, pty)));
    const float pz0 = fmaf(r20, mx0, fmaf(r21, my0, fmaf(r22, mz0, ptz)));
    const float px1 = fmaf(r00, mx1, fmaf(r01, my1, fmaf(r02, mz1, ptx)));
    const float py1 = fmaf(r10, mx1, fmaf(r11, my1, fmaf(r12, mz1, pty)));
    const float pz1 = fmaf(r20, mx1, fmaf(r21, my1, fmaf(r22, mz1, ptz)));
    const float pn0 = fmaf(px0, px0, fmaf(py0, py0, pz0*pz0));
    const float pn1 = fmaf(px1, px1, fmaf(py1, py1, pz1*pz1));

    __syncthreads();

    // min over j of (|g|^2 - 2 p.g); two independent chains per point
    const float BIG = 3.4e38f;
    float m0a = BIG, m0b = BIG, m1a = BIG, m1b = BIG;
    #pragma unroll 4
    for (int j = 0; j < NP; j += 2) {
        const float4 Ga = g4[j];
        const float4 Gb = g4[j + 1];
        const float d0a = fmaf(px0, Ga.x, fmaf(py0, Ga.y, fmaf(pz0, Ga.z, Ga.w)));
        const float d1a = fmaf(px1, Ga.x, fmaf(py1, Ga.y, fmaf(pz1, Ga.z, Ga.w)));
        const float d0b = fmaf(px0, Gb.x, fmaf(py0, Gb.y, fmaf(pz0, Gb.z, Gb.w)));
        const float d1b = fmaf(px1, Gb.x, fmaf(py1, Gb.y, fmaf(pz1, Gb.z, Gb.w)));
        m0a = fminf(m0a, d0a);
        m1a = fminf(m1a, d1a);
        m0b = fminf(m0b, d0b);
        m1b = fminf(m1b, d1b);
    }
    const float dmin0 = fminf(m0a, m0b) + pn0;
    const float dmin1 = fminf(m1a, m1b) + pn1;

    float sum = sqrtf(fmaxf(dmin0, 0.f)) + sqrtf(fmaxf(dmin1, 0.f));

    // Block reduction: wave shuffle (width 64), then LDS across 4 waves
    for (int off = 32; off; off >>= 1) sum += __shfl_down(sum, off, 64);
    __shared__ float wsum[4];
    if ((tid & 63) == 0) wsum[tid >> 6] = sum;
    __syncthreads();
    if (tid == 0) {
        const float s = wsum[0] + wsum[1] + wsum[2] + wsum[3];
        const float add_ij = s * (1.f / NP);
        const float ps = pred_s[b * HW + pix];
        partials[bn] = add_ij * ps - SW * logf(ps);
    }
}

__global__ __launch_bounds__(512) void finalize_kernel(
    const float* __restrict__ partials, float* __restrict__ out)
{
    const int tid = threadIdx.x;
    float v = (tid < BS * NS) ? partials[tid] : 0.f;
    for (int off = 32; off; off >>= 1) v += __shfl_down(v, off, 64);
    __shared__ float ws[8];
    if ((tid & 63) == 0) ws[tid >> 6] = v;
    __syncthreads();
    if (tid == 0) {
        float s = 0.f;
        #pragma unroll
        for (int i = 0; i < 8; ++i) s += ws[i];
        s *= 1.f / (float)(BS * NS);
        if (isinf(s) || isnan(s)) s = 0.f;
        out[0] = s;
    }
}

extern "C" void kernel_launch(void* const* d_in, const int* in_sizes, int n_in,
                              void* d_out, int out_size, void* d_ws, size_t ws_size,
                              hipStream_t stream) {
    const float* pred_r    = (const float*)d_in[0];
    const float* pred_t    = (const float*)d_in[1];
    const float* pred_s    = (const float*)d_in[2];
    // d_in[3] = mask (all ones; reference math ignores it)
    const float* gt_r      = (const float*)d_in[4];
    const float* gt_t      = (const float*)d_in[5];
    const float* model_xyz = (const float*)d_in[6];
    // d_in[7] = cls_ids (unused)

    float* partials = (float*)d_ws;   // BS*NS floats
    float* out      = (float*)d_out;

    add_loss_kernel<<<BS * NS, 256, 0, stream>>>(
        pred_r, pred_t, pred_s, gt_r, gt_t, model_xyz, partials);
    finalize_kernel<<<1, 512, 0, stream>>>(partials, out);
}